// Round 5
// baseline (209.065 us; speedup 1.0000x reference)
//
#include <hip/hip_runtime.h>

// BilinearMixture: out[e,c] = sum_d u[uu,d]*v[vv,d]*M[d,c] + u_bias[uu,c] + v_bias[vv,c]
// R4 finding: byte-bound at ~3.7 TB/s random-line L2-fill (R2 fp32 hit the
// same ceiling). R5: int8 rows with per-row scale -> 64 B/row (one dword per
// lane in the 16-lane group), tables 19.2 -> 9.6 MB. Accuracy ~= fp16 path
// (per-row scale keeps RMS quant err ~0.7%, 3-4x better than fp8).
// Keeps R4's proven structure: 16 lanes/edge, 2-edge ILP, index prefetch,
// K=3 DPP reduction (VALU-rate, no DS pipe), scalars applied post-reduction.

template <int CTRL>
__device__ __forceinline__ float dpp_add(float x) {
    int t = __builtin_amdgcn_update_dpp(0, __float_as_int(x), CTRL, 0xF, 0xF, true);
    return x + __int_as_float(t);
}
template <int CTRL>
__device__ __forceinline__ float dpp_max(float x) {
    int t = __builtin_amdgcn_update_dpp(0, __float_as_int(x), CTRL, 0xF, 0xF, true);
    return fmaxf(x, __int_as_float(t));
}

// Sum (a,b,c) across each 16-lane group: xor1, xor2 (quad_perm), ror4, ror8.
__device__ __forceinline__ void reduce16_3(float& a, float& b, float& c) {
    a = dpp_add<0xB1>(a);  b = dpp_add<0xB1>(b);  c = dpp_add<0xB1>(c);
    a = dpp_add<0x4E>(a);  b = dpp_add<0x4E>(b);  c = dpp_add<0x4E>(c);
    a = dpp_add<0x124>(a); b = dpp_add<0x124>(b); c = dpp_add<0x124>(c);
    a = dpp_add<0x128>(a); b = dpp_add<0x128>(b); c = dpp_add<0x128>(c);
}
__device__ __forceinline__ float reduce16_max(float x) {
    x = dpp_max<0xB1>(x); x = dpp_max<0x4E>(x);
    x = dpp_max<0x124>(x); x = dpp_max<0x128>(x);
    return x;
}

// ---------- quantization: fp32 rows -> int8 (packed dword/lane) + scale ----
// One 16-lane group per row; lane sl owns 4 elems -> 1 packed int.
__global__ __launch_bounds__(256) void quantize_tables_i8(
    const float* __restrict__ u_feat, const float* __restrict__ v_feat,
    int* __restrict__ u_q, int* __restrict__ v_q,
    float* __restrict__ u_s, float* __restrict__ v_s,
    int nrow_u, int nrow_v)
{
    const int tid   = blockIdx.x * blockDim.x + threadIdx.x;
    const int sl    = threadIdx.x & 15;
    const int group = tid >> 4;
    const int ng    = (gridDim.x * blockDim.x) >> 4;
    const int ntot  = nrow_u + nrow_v;

    for (int r = group; r < ntot; r += ng) {
        const bool  isU = (r < nrow_u);
        const int   rr  = isU ? r : r - nrow_u;
        const float* src = (isU ? u_feat : v_feat) + (size_t)rr * 64 + sl * 4;
        const float4 x = *reinterpret_cast<const float4*>(src);

        float am = fmaxf(fmaxf(fabsf(x.x), fabsf(x.y)),
                         fmaxf(fabsf(x.z), fabsf(x.w)));
        am = reduce16_max(am);
        am = fmaxf(am, 1e-20f);
        const float inv   = 127.0f / am;
        const float scale = am / 127.0f;

        const int b0 = (int)rintf(x.x * inv);
        const int b1 = (int)rintf(x.y * inv);
        const int b2 = (int)rintf(x.z * inv);
        const int b3 = (int)rintf(x.w * inv);
        const int packed = (b0 & 255) | ((b1 & 255) << 8) |
                           ((b2 & 255) << 16) | ((b3 & 255) << 24);

        (isU ? u_q : v_q)[(size_t)rr * 16 + sl] = packed;
        if (sl == 0) (isU ? u_s : v_s)[rr] = scale;
    }
}

__device__ __forceinline__ void unpack4(int t, float& f0, float& f1, float& f2, float& f3) {
    f0 = (float)((t << 24) >> 24);
    f1 = (float)((t << 16) >> 24);
    f2 = (float)((t <<  8) >> 24);
    f3 = (float)( t        >> 24);
}

// ---------- main kernel: int8 gathers (64B/row), fp32 math ----------
__global__ __launch_bounds__(256) void bilinear_edges_i8(
    const int* __restrict__ u_q, const int* __restrict__ v_q,
    const float* __restrict__ u_s, const float* __restrict__ v_s,
    const float* __restrict__ W, const float* __restrict__ scalars,
    const float* __restrict__ u_bias, const float* __restrict__ v_bias,
    const int* __restrict__ u_idx, const int* __restrict__ v_idx,
    float* __restrict__ out, int E)
{
    const int tid    = blockIdx.x * blockDim.x + threadIdx.x;
    const int sl     = threadIdx.x & 15;
    const int group  = tid >> 4;
    const int ngroup = (gridDim.x * blockDim.x) >> 4;
    const int step   = ngroup * 2;

    // Per-lane W slice: w[k][j] = W[k, sl*4+j]
    const int d0 = sl * 4;
    float w0[4], w1[4], w2[4];
    #pragma unroll
    for (int j = 0; j < 4; ++j) {
        w0[j] = W[0 * 64 + d0 + j];
        w1[j] = W[1 * 64 + d0 + j];
        w2[j] = W[2 * 64 + d0 + j];
    }
    float s0 = 0.f, s1 = 0.f, s2 = 0.f;
    if (sl < 5) { s0 = scalars[0 * 5 + sl]; s1 = scalars[1 * 5 + sl]; s2 = scalars[2 * 5 + sl]; }

    int e0 = group * 2;
    if (e0 >= E) return;

    int uu0 = u_idx[e0];
    int vv0 = v_idx[e0];
    int uu1 = (e0 + 1 < E) ? u_idx[e0 + 1] : uu0;
    int vv1 = (e0 + 1 < E) ? v_idx[e0 + 1] : vv0;

    for (; e0 < E; e0 += step) {
        const int  e1   = e0 + 1;
        const bool has1 = (e1 < E);
        const int cu0 = uu0, cv0 = vv0, cu1 = uu1, cv1 = vv1;

        // Row gathers: one dword/lane -> 64B contiguous per row, 4 in flight.
        const int qu0 = u_q[(size_t)cu0 * 16 + sl];
        const int qv0 = v_q[(size_t)cv0 * 16 + sl];
        const int qu1 = u_q[(size_t)cu1 * 16 + sl];
        const int qv1 = v_q[(size_t)cv1 * 16 + sl];

        // Prefetch next iteration's indices.
        const int en = e0 + step;
        if (en < E) {
            uu0 = u_idx[en];
            vv0 = v_idx[en];
            const int en1 = en + 1;
            uu1 = (en1 < E) ? u_idx[en1] : uu0;
            vv1 = (en1 < E) ? v_idx[en1] : vv0;
        }

        // Scales + biases for writer lanes (all L2-resident tables).
        float ub0 = 0.f, vb0 = 0.f, ub1 = 0.f, vb1 = 0.f;
        float ss0 = 0.f, ss1 = 0.f;
        if (sl < 5) {
            ss0 = u_s[cu0] * v_s[cv0];
            ss1 = u_s[cu1] * v_s[cv1];
            ub0 = u_bias[(size_t)cu0 * 5 + sl];
            vb0 = v_bias[(size_t)cv0 * 5 + sl];
            ub1 = u_bias[(size_t)cu1 * 5 + sl];
            vb1 = v_bias[(size_t)cv1 * 5 + sl];
        }

        float ua0, ua1, ua2, ua3, va0, va1, va2, va3;
        float ub0f, ub1f, ub2f, ub3f, vb0f, vb1f, vb2f, vb3f;
        unpack4(qu0, ua0, ua1, ua2, ua3);
        unpack4(qv0, va0, va1, va2, va3);
        unpack4(qu1, ub0f, ub1f, ub2f, ub3f);
        unpack4(qv1, vb0f, vb1f, vb2f, vb3f);

        const float a0 = ua0 * va0, a1 = ua1 * va1, a2 = ua2 * va2, a3 = ua3 * va3;
        const float b0 = ub0f * vb0f, b1 = ub1f * vb1f, b2 = ub2f * vb2f, b3 = ub3f * vb3f;

        // K=3 basis partials (quantized domain); scale applied after reduce.
        float qa0 = a0*w0[0] + a1*w0[1] + a2*w0[2] + a3*w0[3];
        float qa1 = a0*w1[0] + a1*w1[1] + a2*w1[2] + a3*w1[3];
        float qa2 = a0*w2[0] + a1*w2[1] + a2*w2[2] + a3*w2[3];
        float qb0 = b0*w0[0] + b1*w0[1] + b2*w0[2] + b3*w0[3];
        float qb1 = b0*w1[0] + b1*w1[1] + b2*w1[2] + b3*w1[3];
        float qb2 = b0*w2[0] + b1*w2[1] + b2*w2[2] + b3*w2[3];

        reduce16_3(qa0, qa1, qa2);
        reduce16_3(qb0, qb1, qb2);

        if (sl < 5) {
            out[(size_t)e0 * 5 + sl] = (qa0 * s0 + qa1 * s1 + qa2 * s2) * ss0 + ub0 + vb0;
            if (has1)
                out[(size_t)e1 * 5 + sl] = (qb0 * s0 + qb1 * s1 + qb2 * s2) * ss1 + ub1 + vb1;
        }
    }
}

// ---------- fallback: direct fp32 (only if ws too small; normally unused) ---
__global__ __launch_bounds__(256) void bilinear_edges_f32(
    const float* __restrict__ u_feat, const float* __restrict__ v_feat,
    const float* __restrict__ W, const float* __restrict__ scalars,
    const float* __restrict__ u_bias, const float* __restrict__ v_bias,
    const int* __restrict__ u_idx, const int* __restrict__ v_idx,
    float* __restrict__ out, int E)
{
    const int tid    = blockIdx.x * blockDim.x + threadIdx.x;
    const int sl     = threadIdx.x & 15;
    const int group  = tid >> 4;
    const int ngroup = (gridDim.x * blockDim.x) >> 4;

    const int d0 = sl * 4;
    float w0[4], w1[4], w2[4];
    #pragma unroll
    for (int j = 0; j < 4; ++j) {
        w0[j] = W[0 * 64 + d0 + j];
        w1[j] = W[1 * 64 + d0 + j];
        w2[j] = W[2 * 64 + d0 + j];
    }
    float s0 = 0.f, s1 = 0.f, s2 = 0.f;
    if (sl < 5) { s0 = scalars[0 * 5 + sl]; s1 = scalars[1 * 5 + sl]; s2 = scalars[2 * 5 + sl]; }

    for (int e = group; e < E; e += ngroup) {
        const int uu = u_idx[e];
        const int vv = v_idx[e];
        const float4 u4 = *reinterpret_cast<const float4*>(u_feat + (size_t)uu * 64 + d0);
        const float4 v4 = *reinterpret_cast<const float4*>(v_feat + (size_t)vv * 64 + d0);
        float ub = 0.f, vb = 0.f;
        if (sl < 5) { ub = u_bias[(size_t)uu * 5 + sl]; vb = v_bias[(size_t)vv * 5 + sl]; }

        const float p0 = u4.x * v4.x, p1 = u4.y * v4.y,
                    p2 = u4.z * v4.z, p3 = u4.w * v4.w;
        float q0 = p0*w0[0] + p1*w0[1] + p2*w0[2] + p3*w0[3];
        float q1 = p0*w1[0] + p1*w1[1] + p2*w1[2] + p3*w1[3];
        float q2 = p0*w2[0] + p1*w2[1] + p2*w2[2] + p3*w2[3];
        reduce16_3(q0, q1, q2);
        if (sl < 5)
            out[(size_t)e * 5 + sl] = q0 * s0 + q1 * s1 + q2 * s2 + ub + vb;
    }
}

extern "C" void kernel_launch(void* const* d_in, const int* in_sizes, int n_in,
                              void* d_out, int out_size, void* d_ws, size_t ws_size,
                              hipStream_t stream) {
    const float* u_feat  = (const float*)d_in[0];
    const float* v_feat  = (const float*)d_in[1];
    const float* W       = (const float*)d_in[2];
    const float* scalars = (const float*)d_in[3];
    const float* u_bias  = (const float*)d_in[4];
    const float* v_bias  = (const float*)d_in[5];
    const int*   u_idx   = (const int*)d_in[6];
    const int*   v_idx   = (const int*)d_in[7];
    float*       out     = (float*)d_out;

    const int nu = in_sizes[0];          // NUM_USERS * 64
    const int nv = in_sizes[1];          // NUM_ITEMS * 64
    const int E  = in_sizes[6];          // 2,000,000 edges
    const int nrow_u = nu / 64;
    const int nrow_v = nv / 64;

    // Workspace layout: u_q[nu ints/4... = nrow_u*16 ints], v_q, u_s, v_s.
    const size_t q_ints  = (size_t)(nrow_u + nrow_v) * 16;
    const size_t ws_need = q_ints * sizeof(int)
                         + (size_t)(nrow_u + nrow_v) * sizeof(float);

    if (ws_size >= ws_need) {
        int*   u_q = (int*)d_ws;
        int*   v_q = u_q + (size_t)nrow_u * 16;
        float* u_s = (float*)(v_q + (size_t)nrow_v * 16);
        float* v_s = u_s + nrow_u;

        quantize_tables_i8<<<2048, 256, 0, stream>>>(
            u_feat, v_feat, u_q, v_q, u_s, v_s, nrow_u, nrow_v);
        bilinear_edges_i8<<<2048, 256, 0, stream>>>(
            u_q, v_q, u_s, v_s, W, scalars, u_bias, v_bias, u_idx, v_idx, out, E);
    } else {
        bilinear_edges_f32<<<2048, 256, 0, stream>>>(
            u_feat, v_feat, W, scalars, u_bias, v_bias, u_idx, v_idx, out, E);
    }
}